// Round 1
// baseline (881.109 us; speedup 1.0000x reference)
//
#include <hip/hip_runtime.h>

// HamGraphConvolution: N=100k nodes, D=64 feats, H=4 heads (DK=16), E=1.6M edges.
// xt = c1*x + c2*(x@W^T)  (Hamiltonian 4-step linear recurrence folded)
// GAT-style attention normalized over col, aggregated over row.
// Softmax max-subtraction skipped: shift-invariant, eps 1e-16 unreachable.

#define LRELU(v) ((v) > 0.0f ? (v) : 0.2f * (v))

__global__ __launch_bounds__(256) void k_init(float* __restrict__ out,
                                              float* __restrict__ denom, int n) {
    int i = blockIdx.x * 256 + threadIdx.x;
    if (i < n * 64) out[i] = 0.0f;
    if (i < n * 4) denom[i] = 0.0f;
}

__global__ __launch_bounds__(256) void k_node(const float* __restrict__ x,
                                              const float* __restrict__ W,
                                              const float* __restrict__ a,
                                              float* __restrict__ xt,
                                              float* __restrict__ s_src,
                                              float* __restrict__ s_dst,
                                              int n, float c1, float c2) {
    __shared__ float Ws[64 * 65];  // padded: bank (lane+k)%32 -> 2-way (free)
    for (int i = threadIdx.x; i < 64 * 64; i += 256) {
        int r = i >> 6, c = i & 63;
        Ws[r * 65 + c] = W[i];
    }
    __syncthreads();
    int wave = threadIdx.x >> 6;
    int lane = threadIdx.x & 63;
    float a_s = a[lane & 15];
    float a_d = a[16 + (lane & 15)];
    int node = blockIdx.x * 4 + wave;
    if (node >= n) return;

    float xv = x[node * 64 + lane];
    // p[lane] = sum_k x[k] * W[lane][k]
    float p = 0.0f;
#pragma unroll
    for (int k = 0; k < 64; ++k) {
        float xk = __shfl(xv, k, 64);
        p = fmaf(xk, Ws[lane * 65 + k], p);
    }
    float xtv = c1 * xv + c2 * p;
    xt[node * 64 + lane] = xtv;

    // per-head (16-lane group) reductions: s_src = sum xt*a[:16], s_dst = sum xt*a[16:]
    float ss = xtv * a_s;
    float sd = xtv * a_d;
#pragma unroll
    for (int off = 8; off >= 1; off >>= 1) {
        ss += __shfl_xor(ss, off, 64);
        sd += __shfl_xor(sd, off, 64);
    }
    if ((lane & 15) == 0) {
        int h = lane >> 4;
        s_src[node * 4 + h] = ss;
        s_dst[node * 4 + h] = sd;
    }
}

__global__ __launch_bounds__(256) void k_denom(const int* __restrict__ row,
                                               const int* __restrict__ col,
                                               const float* __restrict__ s_src,
                                               const float* __restrict__ s_dst,
                                               float* __restrict__ denom, int e) {
    int idx = blockIdx.x * 256 + threadIdx.x;
    if (idx >= e) return;
    int r = row[idx], c = col[idx];
    float4 ss = *(const float4*)(s_src + (size_t)r * 4);
    float4 sd = *(const float4*)(s_dst + (size_t)c * 4);
    float e0 = __expf(LRELU(ss.x + sd.x));
    float e1 = __expf(LRELU(ss.y + sd.y));
    float e2 = __expf(LRELU(ss.z + sd.z));
    float e3 = __expf(LRELU(ss.w + sd.w));
    atomicAdd(&denom[c * 4 + 0], e0);
    atomicAdd(&denom[c * 4 + 1], e1);
    atomicAdd(&denom[c * 4 + 2], e2);
    atomicAdd(&denom[c * 4 + 3], e3);
}

__global__ __launch_bounds__(256) void k_aggr(const int* __restrict__ row,
                                              const int* __restrict__ col,
                                              const float* __restrict__ s_src,
                                              const float* __restrict__ s_dst,
                                              const float* __restrict__ denom,
                                              const float* __restrict__ xt,
                                              float* __restrict__ out, int e) {
    int edge = blockIdx.x * 4 + (threadIdx.x >> 6);
    if (edge >= e) return;
    int lane = threadIdx.x & 63;
    int r = row[edge], c = col[edge];
    // same-address across the wave -> broadcast, 1 transaction each
    float4 ss = *(const float4*)(s_src + (size_t)r * 4);
    float4 sd = *(const float4*)(s_dst + (size_t)c * 4);
    float4 dn = *(const float4*)(denom + (size_t)c * 4);
    float w = __expf(LRELU(ss.x + sd.x)) / (dn.x + 1e-16f) +
              __expf(LRELU(ss.y + sd.y)) / (dn.y + 1e-16f) +
              __expf(LRELU(ss.z + sd.z)) / (dn.z + 1e-16f) +
              __expf(LRELU(ss.w + sd.w)) / (dn.w + 1e-16f);
    w *= 0.25f;
    atomicAdd(&out[(size_t)r * 64 + lane], w * xt[(size_t)c * 64 + lane]);
}

extern "C" void kernel_launch(void* const* d_in, const int* in_sizes, int n_in,
                              void* d_out, int out_size, void* d_ws, size_t ws_size,
                              hipStream_t stream) {
    const float* x = (const float*)d_in[0];
    const int* ei = (const int*)d_in[1];
    // d_in[2] = edge_weight: unused by the reference
    const float* W = (const float*)d_in[3];
    const float* a = (const float*)d_in[4];
    int n = in_sizes[0] / 64;
    int e = in_sizes[1] / 2;
    const int* row = ei;
    const int* col = ei + e;
    float* out = (float*)d_out;

    float* xt = (float*)d_ws;                   // n*64 floats
    float* s_src = xt + (size_t)n * 64;         // n*4
    float* s_dst = s_src + (size_t)n * 4;       // n*4
    float* denom = s_dst + (size_t)n * 4;       // n*4

    // Fold the 4-step (q,p) <- (q+0.25p, p-0.25q) recurrence: xt = aq*x + bq*(x@W^T)
    float aq = 1.f, bq = 0.f, ap = 0.f, bp = 1.f;
    for (int i = 0; i < 4; ++i) {
        float naq = aq + 0.25f * ap, nbq = bq + 0.25f * bp;
        float nap = ap - 0.25f * aq, nbp = bp - 0.25f * bq;
        aq = naq; bq = nbq; ap = nap; bp = nbp;
    }

    k_init<<<(n * 64 + 255) / 256, 256, 0, stream>>>(out, denom, n);
    k_node<<<(n + 3) / 4, 256, 0, stream>>>(x, W, a, xt, s_src, s_dst, n, aq, bq);
    k_denom<<<(e + 255) / 256, 256, 0, stream>>>(row, col, s_src, s_dst, denom, e);
    k_aggr<<<(e + 3) / 4, 256, 0, stream>>>(row, col, s_src, s_dst, denom, xt, out, e);
}